// Round 2
// baseline (1274.272 us; speedup 1.0000x reference)
//
#include <hip/hip_runtime.h>
#include <hip/hip_bf16.h>

#define NEG_SLOPE 0.2f
#define LRELU(v) ((v) > 0.f ? (v) : NEG_SLOPE * (v))

static inline int cdiv(int a, int b) { return (a + b - 1) / b; }

// ---- order-preserving float<->uint for atomicMax on floats ----
__device__ __forceinline__ unsigned f2ord(float f) {
    unsigned u = __float_as_uint(f);
    return (u & 0x80000000u) ? ~u : (u | 0x80000000u);
}
__device__ __forceinline__ float ord2f(unsigned u) {
    return (u & 0x80000000u) ? __uint_as_float(u & 0x7fffffffu) : __uint_as_float(~u);
}
// f2ord(-inf) = ~0xFF800000 = 0x007FFFFF
#define ORD_NEG_INF 0x007FFFFFu

// =================== CSR build ===================
__global__ __launch_bounds__(256) void k_zero_int(int* p, int n) {
    int i = blockIdx.x * 256 + threadIdx.x;
    if (i < n) p[i] = 0;
}

__global__ __launch_bounds__(256) void k_degree(const int* __restrict__ ei, int E, int ET,
                                                int* __restrict__ deg) {
    int i = blockIdx.x * 256 + threadIdx.x;
    if (i >= ET) return;
    int d = (i < E) ? ei[E + i] : (i - E);  // self loops appended
    atomicAdd(&deg[d], 1);
}

// chunked exclusive scan: 256 thr x 8 items = 2048/block
__global__ __launch_bounds__(256) void k_scan1(const int* __restrict__ deg, int* __restrict__ part,
                                               int* __restrict__ bsum, int N) {
    __shared__ int sa[256], sb[256];
    int t = threadIdx.x, b = blockIdx.x;
    int base = b * 2048 + t * 8;
    int v[8]; int s = 0;
#pragma unroll
    for (int i = 0; i < 8; i++) { int idx = base + i; v[i] = (idx < N) ? deg[idx] : 0; s += v[i]; }
    sa[t] = s; __syncthreads();
    int* pin = sa; int* pout = sb;
    for (int off = 1; off < 256; off <<= 1) {
        pout[t] = (t >= off) ? pin[t] + pin[t - off] : pin[t];
        __syncthreads();
        int* tmp = pin; pin = pout; pout = tmp;
    }
    int exc = (t == 0) ? 0 : pin[t - 1];
    if (t == 255) bsum[b] = pin[255];
    int run = exc;
#pragma unroll
    for (int i = 0; i < 8; i++) { int idx = base + i; if (idx < N) part[idx] = run; run += v[i]; }
}

__global__ void k_scan2(int* bsum, int nb, int* offs, int N) {
    if (threadIdx.x == 0 && blockIdx.x == 0) {
        int run = 0;
        for (int i = 0; i < nb; i++) { int t = bsum[i]; bsum[i] = run; run += t; }
        offs[N] = run;  // == ET
    }
}

__global__ __launch_bounds__(256) void k_scan3(int* __restrict__ offs, const int* __restrict__ bsum,
                                               int* __restrict__ cursor, int N) {
    int i = blockIdx.x * 256 + threadIdx.x;
    if (i >= N) return;
    int v = offs[i] + bsum[i / 2048];
    offs[i] = v;
    cursor[i] = v;
}

__global__ __launch_bounds__(256) void k_scatter(const int* __restrict__ ei, int E, int ET,
                                                 int* __restrict__ cursor, int* __restrict__ ssrc) {
    int i = blockIdx.x * 256 + threadIdx.x;
    if (i >= ET) return;
    int s = (i < E) ? ei[i] : (i - E);
    int d = (i < E) ? ei[E + i] : (i - E);
    int pos = atomicAdd(&cursor[d], 1);
    ssrc[pos] = s;
}

// =================== GEMM: h[N,M] = x[N,128] @ W[128,M] ===================
// 4x4 register blocking, xs staged transposed in LDS, W staged in 64-row halves.
template <int M, int TR>
__global__ __launch_bounds__(256) void k_gemm(const float* __restrict__ x,
                                              const float* __restrict__ W,
                                              float* __restrict__ h, int N) {
    __shared__ float xs[128 * TR];  // xs[k][r], k = 0..127 (full K staged once)
    __shared__ float ws[64 * M];    // ws[k][j], one 64-row half of W at a time
    int t = threadIdx.x;
    int row0 = blockIdx.x * TR;

    {   // load x tile transposed: thread -> row = t%TR, kvec group = t/TR
        int r = t % TR;
        int kv0 = t / TR;
        const int GK = 256 / TR;
        int row = row0 + r;
        for (int kv = kv0; kv < 32; kv += GK) {
            float4 v = make_float4(0.f, 0.f, 0.f, 0.f);
            if (row < N) v = *(const float4*)(x + (size_t)row * 128 + kv * 4);
            xs[(kv * 4 + 0) * TR + r] = v.x;
            xs[(kv * 4 + 1) * TR + r] = v.y;
            xs[(kv * 4 + 2) * TR + r] = v.z;
            xs[(kv * 4 + 3) * TR + r] = v.w;
        }
    }

    constexpr int CQ = M / 4;
    int tx = t % CQ, ty = t / CQ;
    int j0 = tx * 4, r0 = ty * 4;
    float acc[4][4];
#pragma unroll
    for (int a = 0; a < 4; a++)
#pragma unroll
        for (int b = 0; b < 4; b++) acc[a][b] = 0.f;

    for (int ks = 0; ks < 128; ks += 64) {
        __syncthreads();
        const float4* wg = (const float4*)(W + (size_t)ks * M);
        float4* wl = (float4*)ws;
        for (int i = t; i < 64 * M / 4; i += 256) wl[i] = wg[i];
        __syncthreads();
#pragma unroll 8
        for (int k = 0; k < 64; k++) {
            // NOTE: xs holds the full K=128 tile; index with (ks + k).
            float4 xv = *(const float4*)(xs + (ks + k) * TR + r0);
            float4 wv = *(const float4*)(ws + k * M + j0);
            float xr[4] = {xv.x, xv.y, xv.z, xv.w};
            float wr[4] = {wv.x, wv.y, wv.z, wv.w};
#pragma unroll
            for (int a = 0; a < 4; a++)
#pragma unroll
                for (int b = 0; b < 4; b++) acc[a][b] += xr[a] * wr[b];
        }
    }
#pragma unroll
    for (int a = 0; a < 4; a++) {
        int row = row0 + r0 + a;
        if (row < N)
            *(float4*)(h + (size_t)row * M + j0) =
                make_float4(acc[a][0], acc[a][1], acc[a][2], acc[a][3]);
    }
}

// =================== per-node attention projections ===================
template <int H>
__global__ __launch_bounds__(256) void k_alpha(const float* __restrict__ h,
                                               const float* __restrict__ a_src,
                                               const float* __restrict__ a_dst,
                                               float* __restrict__ as, float* __restrict__ ad,
                                               int N) {
    int wid = (blockIdx.x * 256 + threadIdx.x) >> 6;
    int lane = threadIdx.x & 63;
    if (wid >= N * H) return;
    int n = wid / H, hh = wid % H;
    float v = h[(size_t)n * (H * 64) + hh * 64 + lane];
    float s = v * a_src[hh * 64 + lane];
    float d = v * a_dst[hh * 64 + lane];
#pragma unroll
    for (int off = 32; off; off >>= 1) { s += __shfl_down(s, off); d += __shfl_down(d, off); }
    if (lane == 0) { as[wid] = s; ad[wid] = d; }
}

__global__ __launch_bounds__(256) void k_init_sm(unsigned* __restrict__ em, float* __restrict__ den,
                                                 int NH) {
    int i = blockIdx.x * 256 + threadIdx.x;
    if (i < NH) { em[i] = ORD_NEG_INF; den[i] = 0.f; }
}

// =================== segment max / segment expsum over edges ===================
template <int H>
__global__ __launch_bounds__(256) void k_edge_max(const int* __restrict__ ei, int E, int ET,
                                                  const float* __restrict__ as,
                                                  const float* __restrict__ ad,
                                                  unsigned* __restrict__ em) {
    int i = blockIdx.x * 256 + threadIdx.x;
    if (i >= ET) return;
    int s = (i < E) ? ei[i] : (i - E);
    int d = (i < E) ? ei[E + i] : (i - E);
#pragma unroll
    for (int hh = 0; hh < H; hh++) {
        float e = as[s * H + hh] + ad[d * H + hh];
        e = LRELU(e);
        atomicMax(&em[d * H + hh], f2ord(e));
    }
}

template <int H>
__global__ __launch_bounds__(256) void k_edge_sum(const int* __restrict__ ei, int E, int ET,
                                                  const float* __restrict__ as,
                                                  const float* __restrict__ ad,
                                                  const unsigned* __restrict__ em,
                                                  float* __restrict__ den) {
    int i = blockIdx.x * 256 + threadIdx.x;
    if (i >= ET) return;
    int s = (i < E) ? ei[i] : (i - E);
    int d = (i < E) ? ei[E + i] : (i - E);
#pragma unroll
    for (int hh = 0; hh < H; hh++) {
        float e = as[s * H + hh] + ad[d * H + hh];
        e = LRELU(e);
        atomicAdd(&den[d * H + hh], __expf(e - ord2f(em[d * H + hh])));
    }
}

// =================== aggregation: one wave per dst node, lane = channel ===================
template <int H, bool ELU_ACT>
__global__ __launch_bounds__(256) void k_agg(const int* __restrict__ offs,
                                             const int* __restrict__ ssrc,
                                             const float* __restrict__ h,
                                             const float* __restrict__ as,
                                             const float* __restrict__ ad,
                                             const unsigned* __restrict__ em,
                                             const float* __restrict__ den,
                                             const float* __restrict__ bias,
                                             float* __restrict__ z, int N) {
    int d = (blockIdx.x * 256 + threadIdx.x) >> 6;
    int lane = threadIdx.x & 63;
    if (d >= N) return;
    float adh[H], mh[H], idh[H], acc[H];
#pragma unroll
    for (int hh = 0; hh < H; hh++) {
        adh[hh] = ad[d * H + hh];
        mh[hh] = ord2f(em[d * H + hh]);
        idh[hh] = 1.f / den[d * H + hh];
        acc[hh] = 0.f;
    }
    int e0 = offs[d], e1 = offs[d + 1];
    for (int e = e0; e < e1; e++) {
        int s = ssrc[e];
        const float* hs = h + (size_t)s * (H * 64);
#pragma unroll
        for (int hh = 0; hh < H; hh++) {
            float ev = as[s * H + hh] + adh[hh];
            ev = LRELU(ev);
            float a = __expf(ev - mh[hh]) * idh[hh];
            acc[hh] += a * hs[hh * 64 + lane];
        }
    }
#pragma unroll
    for (int hh = 0; hh < H; hh++) {
        float v = acc[hh] + bias[hh * 64 + lane];
        if (ELU_ACT) v = v > 0.f ? v : expm1f(v);
        z[(size_t)d * (H * 64) + hh * 64 + lane] = v;
    }
}

// =================== decode: dot of endpoint embeddings ===================
__global__ __launch_bounds__(256) void k_decode(const int* __restrict__ eli,
                                                const float* __restrict__ z,
                                                float* __restrict__ out, int EL) {
    int wid = (blockIdx.x * 256 + threadIdx.x) >> 6;
    int lane = threadIdx.x & 63;
    if (wid >= EL) return;
    int a = eli[wid], b = eli[EL + wid];
    float p = z[(size_t)a * 64 + lane] * z[(size_t)b * 64 + lane];
#pragma unroll
    for (int off = 32; off; off >>= 1) p += __shfl_down(p, off);
    if (lane == 0) out[wid] = p;
}

extern "C" void kernel_launch(void* const* d_in, const int* in_sizes, int n_in,
                              void* d_out, int out_size, void* d_ws, size_t ws_size,
                              hipStream_t stream) {
    const float* x   = (const float*)d_in[0];
    const int*   ei  = (const int*)d_in[1];
    const int*   eli = (const int*)d_in[2];
    const float* W1  = (const float*)d_in[3];
    const float* as1 = (const float*)d_in[4];
    const float* ad1 = (const float*)d_in[5];
    const float* b1  = (const float*)d_in[6];
    const float* W2  = (const float*)d_in[7];
    const float* as2 = (const float*)d_in[8];
    const float* ad2 = (const float*)d_in[9];
    const float* b2  = (const float*)d_in[10];

    int N  = in_sizes[0] / 128;
    int E  = in_sizes[1] / 2;
    int EL = in_sizes[2] / 2;
    int ET = E + N;

    char* ws = (char*)d_ws;
    size_t off = 0;
    auto alloc = [&](size_t nbytes) -> void* {
        void* p = ws + off;
        off += (nbytes + 255) & ~(size_t)255;
        return p;
    };
    float*    Hbuf = (float*)alloc((size_t)N * 128 * 4);  // h1 then h2
    float*    Zbuf = (float*)alloc((size_t)N * 128 * 4);  // z1 then z2
    float*    AS   = (float*)alloc((size_t)N * 2 * 4);
    float*    AD   = (float*)alloc((size_t)N * 2 * 4);
    unsigned* EM   = (unsigned*)alloc((size_t)N * 2 * 4);
    float*    DEN  = (float*)alloc((size_t)N * 2 * 4);
    int*      DEG  = (int*)alloc((size_t)N * 4);          // reused as scatter cursor
    int*      OFF  = (int*)alloc((size_t)(N + 1) * 4);
    int*      SSRC = (int*)alloc((size_t)ET * 4);
    int*      BSUM = (int*)alloc(1024);

    // ---- CSR build (shared by both layers) ----
    k_zero_int<<<cdiv(N, 256), 256, 0, stream>>>(DEG, N);
    k_degree<<<cdiv(ET, 256), 256, 0, stream>>>(ei, E, ET, DEG);
    int nb = cdiv(N, 2048);
    k_scan1<<<nb, 256, 0, stream>>>(DEG, OFF, BSUM, N);
    k_scan2<<<1, 64, 0, stream>>>(BSUM, nb, OFF, N);
    k_scan3<<<cdiv(N, 256), 256, 0, stream>>>(OFF, BSUM, DEG, N);
    k_scatter<<<cdiv(ET, 256), 256, 0, stream>>>(ei, E, ET, DEG, SSRC);

    // ---- layer 1: heads=2, C=64, ELU ----
    k_gemm<128, 32><<<cdiv(N, 32), 256, 0, stream>>>(x, W1, Hbuf, N);
    k_alpha<2><<<cdiv(N * 2, 4), 256, 0, stream>>>(Hbuf, as1, ad1, AS, AD, N);
    k_init_sm<<<cdiv(N * 2, 256), 256, 0, stream>>>(EM, DEN, N * 2);
    k_edge_max<2><<<cdiv(ET, 256), 256, 0, stream>>>(ei, E, ET, AS, AD, EM);
    k_edge_sum<2><<<cdiv(ET, 256), 256, 0, stream>>>(ei, E, ET, AS, AD, EM, DEN);
    k_agg<2, true><<<cdiv(N, 4), 256, 0, stream>>>(OFF, SSRC, Hbuf, AS, AD, EM, DEN, b1, Zbuf, N);

    // ---- layer 2: heads=1, C=64, no activation ----
    k_gemm<64, 64><<<cdiv(N, 64), 256, 0, stream>>>(Zbuf, W2, Hbuf, N);
    k_alpha<1><<<cdiv(N, 4), 256, 0, stream>>>(Hbuf, as2, ad2, AS, AD, N);
    k_init_sm<<<cdiv(N, 256), 256, 0, stream>>>(EM, DEN, N);
    k_edge_max<1><<<cdiv(ET, 256), 256, 0, stream>>>(ei, E, ET, AS, AD, EM);
    k_edge_sum<1><<<cdiv(ET, 256), 256, 0, stream>>>(ei, E, ET, AS, AD, EM, DEN);
    // z2 overwrites Zbuf (z1 no longer needed; k_agg reads only Hbuf + per-node stats)
    k_agg<1, false><<<cdiv(N, 4), 256, 0, stream>>>(OFF, SSRC, Hbuf, AS, AD, EM, DEN, b2, Zbuf, N);

    // ---- decode ----
    k_decode<<<cdiv(EL, 4), 256, 0, stream>>>(eli, Zbuf, (float*)d_out, EL);
}

// Round 3
// 653.188 us; speedup vs baseline: 1.9508x; 1.9508x over previous
//
#include <hip/hip_runtime.h>
#include <hip/hip_bf16.h>

#define NEG_SLOPE 0.2f
#define LRELU(v) ((v) > 0.f ? (v) : NEG_SLOPE * (v))

static inline int cdiv(int a, int b) { return (a + b - 1) / b; }

// =================== wave-wide butterfly reductions (64 lanes) ===================
__device__ __forceinline__ float wmax(float v) {
#pragma unroll
    for (int o = 32; o; o >>= 1) v = fmaxf(v, __shfl_xor(v, o));
    return v;
}
__device__ __forceinline__ float wsum(float v) {
#pragma unroll
    for (int o = 32; o; o >>= 1) v += __shfl_xor(v, o);
    return v;
}

// =================== CSR build ===================
__global__ __launch_bounds__(256) void k_zero_int(int* p, int n) {
    int i = blockIdx.x * 256 + threadIdx.x;
    if (i < n) p[i] = 0;
}

__global__ __launch_bounds__(256) void k_degree(const int* __restrict__ ei, int E, int ET,
                                                int* __restrict__ deg) {
    int i = blockIdx.x * 256 + threadIdx.x;
    if (i >= ET) return;
    int d = (i < E) ? ei[E + i] : (i - E);  // self loops appended
    atomicAdd(&deg[d], 1);
}

// chunked exclusive scan: 256 thr x 8 items = 2048/block
__global__ __launch_bounds__(256) void k_scan1(const int* __restrict__ deg, int* __restrict__ part,
                                               int* __restrict__ bsum, int N) {
    __shared__ int sa[256], sb[256];
    int t = threadIdx.x, b = blockIdx.x;
    int base = b * 2048 + t * 8;
    int v[8]; int s = 0;
#pragma unroll
    for (int i = 0; i < 8; i++) { int idx = base + i; v[i] = (idx < N) ? deg[idx] : 0; s += v[i]; }
    sa[t] = s; __syncthreads();
    int* pin = sa; int* pout = sb;
    for (int off = 1; off < 256; off <<= 1) {
        pout[t] = (t >= off) ? pin[t] + pin[t - off] : pin[t];
        __syncthreads();
        int* tmp = pin; pin = pout; pout = tmp;
    }
    int exc = (t == 0) ? 0 : pin[t - 1];
    if (t == 255) bsum[b] = pin[255];
    int run = exc;
#pragma unroll
    for (int i = 0; i < 8; i++) { int idx = base + i; if (idx < N) part[idx] = run; run += v[i]; }
}

__global__ void k_scan2(int* bsum, int nb, int* offs, int N) {
    if (threadIdx.x == 0 && blockIdx.x == 0) {
        int run = 0;
        for (int i = 0; i < nb; i++) { int t = bsum[i]; bsum[i] = run; run += t; }
        offs[N] = run;  // == ET
    }
}

__global__ __launch_bounds__(256) void k_scan3(int* __restrict__ offs, const int* __restrict__ bsum,
                                               int* __restrict__ cursor, int N) {
    int i = blockIdx.x * 256 + threadIdx.x;
    if (i >= N) return;
    int v = offs[i] + bsum[i / 2048];
    offs[i] = v;
    cursor[i] = v;
}

__global__ __launch_bounds__(256) void k_scatter(const int* __restrict__ ei, int E, int ET,
                                                 int* __restrict__ cursor, int* __restrict__ ssrc) {
    int i = blockIdx.x * 256 + threadIdx.x;
    if (i >= ET) return;
    int s = (i < E) ? ei[i] : (i - E);
    int d = (i < E) ? ei[E + i] : (i - E);
    int pos = atomicAdd(&cursor[d], 1);
    ssrc[pos] = s;
}

// =================== GEMM: h[N,M] = x[N,128] @ W[128,M] ===================
template <int M, int TR>
__global__ __launch_bounds__(256) void k_gemm(const float* __restrict__ x,
                                              const float* __restrict__ W,
                                              float* __restrict__ h, int N) {
    __shared__ float xs[128 * TR];  // xs[k][r], full K staged once
    __shared__ float ws[64 * M];    // ws[k][j], one 64-row half of W at a time
    int t = threadIdx.x;
    int row0 = blockIdx.x * TR;

    {   // load x tile transposed
        int r = t % TR;
        int kv0 = t / TR;
        const int GK = 256 / TR;
        int row = row0 + r;
        for (int kv = kv0; kv < 32; kv += GK) {
            float4 v = make_float4(0.f, 0.f, 0.f, 0.f);
            if (row < N) v = *(const float4*)(x + (size_t)row * 128 + kv * 4);
            xs[(kv * 4 + 0) * TR + r] = v.x;
            xs[(kv * 4 + 1) * TR + r] = v.y;
            xs[(kv * 4 + 2) * TR + r] = v.z;
            xs[(kv * 4 + 3) * TR + r] = v.w;
        }
    }

    constexpr int CQ = M / 4;
    int tx = t % CQ, ty = t / CQ;
    int j0 = tx * 4, r0 = ty * 4;
    float acc[4][4];
#pragma unroll
    for (int a = 0; a < 4; a++)
#pragma unroll
        for (int b = 0; b < 4; b++) acc[a][b] = 0.f;

    for (int ks = 0; ks < 128; ks += 64) {
        __syncthreads();
        const float4* wg = (const float4*)(W + (size_t)ks * M);
        float4* wl = (float4*)ws;
        for (int i = t; i < 64 * M / 4; i += 256) wl[i] = wg[i];
        __syncthreads();
#pragma unroll 8
        for (int k = 0; k < 64; k++) {
            float4 xv = *(const float4*)(xs + (ks + k) * TR + r0);
            float4 wv = *(const float4*)(ws + k * M + j0);
            float xr[4] = {xv.x, xv.y, xv.z, xv.w};
            float wr[4] = {wv.x, wv.y, wv.z, wv.w};
#pragma unroll
            for (int a = 0; a < 4; a++)
#pragma unroll
                for (int b = 0; b < 4; b++) acc[a][b] += xr[a] * wr[b];
        }
    }
#pragma unroll
    for (int a = 0; a < 4; a++) {
        int row = row0 + r0 + a;
        if (row < N)
            *(float4*)(h + (size_t)row * M + j0) =
                make_float4(acc[a][0], acc[a][1], acc[a][2], acc[a][3]);
    }
}

// =================== per-node attention projections ===================
template <int H>
__global__ __launch_bounds__(256) void k_alpha(const float* __restrict__ h,
                                               const float* __restrict__ a_src,
                                               const float* __restrict__ a_dst,
                                               float* __restrict__ as, float* __restrict__ ad,
                                               int N) {
    int wid = (blockIdx.x * 256 + threadIdx.x) >> 6;
    int lane = threadIdx.x & 63;
    if (wid >= N * H) return;
    int n = wid / H, hh = wid % H;
    float v = h[(size_t)n * (H * 64) + hh * 64 + lane];
    float s = v * a_src[hh * 64 + lane];
    float d = v * a_dst[hh * 64 + lane];
#pragma unroll
    for (int off = 32; off; off >>= 1) { s += __shfl_down(s, off); d += __shfl_down(d, off); }
    if (lane == 0) { as[wid] = s; ad[wid] = d; }
}

// =================== fused softmax + aggregation: one wave per dst node ===================
// Online (flash-style) softmax over the dst's edge list; lanes cooperate:
//  - chunk of up to 64 edges: lane e loads ssrc & as[s] (64 gathers in flight)
//  - wave-reduce max & exp-sum, rescale running acc/den
//  - heavy h[src] gather with alpha broadcast via shfl, unrolled x4
template <int H, bool ELU_ACT>
__global__ __launch_bounds__(256) void k_agg_fused(const int* __restrict__ offs,
                                                   const int* __restrict__ ssrc,
                                                   const float* __restrict__ h,
                                                   const float* __restrict__ as,
                                                   const float* __restrict__ ad,
                                                   const float* __restrict__ bias,
                                                   float* __restrict__ z, int N) {
    int d = (blockIdx.x * 256 + threadIdx.x) >> 6;
    int lane = threadIdx.x & 63;
    if (d >= N) return;
    float adh[H], m[H], den[H], acc[H];
#pragma unroll
    for (int hh = 0; hh < H; hh++) {
        adh[hh] = ad[d * H + hh];
        m[hh] = -1e30f; den[hh] = 0.f; acc[hh] = 0.f;
    }
    int e0 = offs[d], e1 = offs[d + 1];
    for (int cb = e0; cb < e1; cb += 64) {
        int ne = min(64, e1 - cb);
        int s_l = 0;
        float eh[H];
#pragma unroll
        for (int hh = 0; hh < H; hh++) eh[hh] = -1e30f;
        if (lane < ne) {
            s_l = ssrc[cb + lane];
#pragma unroll
            for (int hh = 0; hh < H; hh++) {
                float e = as[s_l * H + hh] + adh[hh];
                eh[hh] = LRELU(e);
            }
        }
        float p[H];
#pragma unroll
        for (int hh = 0; hh < H; hh++) {
            float cm = wmax(eh[hh]);
            float nm = fmaxf(m[hh], cm);
            float sc = __expf(m[hh] - nm);  // first chunk: exp(-1e30-nm) = 0
            acc[hh] *= sc; den[hh] *= sc;
            p[hh] = (lane < ne) ? __expf(eh[hh] - nm) : 0.f;
            den[hh] += wsum(p[hh]);
            m[hh] = nm;
        }
        // heavy gather over this chunk's edges, unrolled x4 for MLP latency hiding
        int j = 0;
        for (; j + 4 <= ne; j += 4) {
            int ss[4]; float pp[4][H];
#pragma unroll
            for (int q = 0; q < 4; q++) {
                ss[q] = __shfl(s_l, j + q);
#pragma unroll
                for (int hh = 0; hh < H; hh++) pp[q][hh] = __shfl(p[hh], j + q);
            }
            float hv[4][H];
#pragma unroll
            for (int q = 0; q < 4; q++) {
                const float* hs = h + (size_t)ss[q] * (H * 64);
#pragma unroll
                for (int hh = 0; hh < H; hh++) hv[q][hh] = hs[hh * 64 + lane];
            }
#pragma unroll
            for (int q = 0; q < 4; q++)
#pragma unroll
                for (int hh = 0; hh < H; hh++) acc[hh] += pp[q][hh] * hv[q][hh];
        }
        for (; j < ne; j++) {
            int s = __shfl(s_l, j);
            const float* hs = h + (size_t)s * (H * 64);
#pragma unroll
            for (int hh = 0; hh < H; hh++) acc[hh] += __shfl(p[hh], j) * hs[hh * 64 + lane];
        }
    }
#pragma unroll
    for (int hh = 0; hh < H; hh++) {
        float v = acc[hh] / den[hh] + bias[hh * 64 + lane];
        if (ELU_ACT) v = v > 0.f ? v : expm1f(v);
        z[(size_t)d * (H * 64) + hh * 64 + lane] = v;
    }
}

// =================== decode: dot of endpoint embeddings ===================
__global__ __launch_bounds__(256) void k_decode(const int* __restrict__ eli,
                                                const float* __restrict__ z,
                                                float* __restrict__ out, int EL) {
    int wid = (blockIdx.x * 256 + threadIdx.x) >> 6;
    int lane = threadIdx.x & 63;
    if (wid >= EL) return;
    int a = eli[wid], b = eli[EL + wid];
    float p = z[(size_t)a * 64 + lane] * z[(size_t)b * 64 + lane];
#pragma unroll
    for (int off = 32; off; off >>= 1) p += __shfl_down(p, off);
    if (lane == 0) out[wid] = p;
}

extern "C" void kernel_launch(void* const* d_in, const int* in_sizes, int n_in,
                              void* d_out, int out_size, void* d_ws, size_t ws_size,
                              hipStream_t stream) {
    const float* x   = (const float*)d_in[0];
    const int*   ei  = (const int*)d_in[1];
    const int*   eli = (const int*)d_in[2];
    const float* W1  = (const float*)d_in[3];
    const float* as1 = (const float*)d_in[4];
    const float* ad1 = (const float*)d_in[5];
    const float* b1  = (const float*)d_in[6];
    const float* W2  = (const float*)d_in[7];
    const float* as2 = (const float*)d_in[8];
    const float* ad2 = (const float*)d_in[9];
    const float* b2  = (const float*)d_in[10];

    int N  = in_sizes[0] / 128;
    int E  = in_sizes[1] / 2;
    int EL = in_sizes[2] / 2;
    int ET = E + N;

    char* ws = (char*)d_ws;
    size_t off = 0;
    auto alloc = [&](size_t nbytes) -> void* {
        void* p = ws + off;
        off += (nbytes + 255) & ~(size_t)255;
        return p;
    };
    float*    Hbuf = (float*)alloc((size_t)N * 128 * 4);  // h1 then h2
    float*    Zbuf = (float*)alloc((size_t)N * 128 * 4);  // z1 then z2
    float*    AS   = (float*)alloc((size_t)N * 2 * 4);
    float*    AD   = (float*)alloc((size_t)N * 2 * 4);
    int*      DEG  = (int*)alloc((size_t)N * 4);          // reused as scatter cursor
    int*      OFF  = (int*)alloc((size_t)(N + 1) * 4);
    int*      SSRC = (int*)alloc((size_t)ET * 4);
    int*      BSUM = (int*)alloc(1024);

    // ---- CSR build (shared by both layers) ----
    k_zero_int<<<cdiv(N, 256), 256, 0, stream>>>(DEG, N);
    k_degree<<<cdiv(ET, 256), 256, 0, stream>>>(ei, E, ET, DEG);
    int nb = cdiv(N, 2048);
    k_scan1<<<nb, 256, 0, stream>>>(DEG, OFF, BSUM, N);
    k_scan2<<<1, 64, 0, stream>>>(BSUM, nb, OFF, N);
    k_scan3<<<cdiv(N, 256), 256, 0, stream>>>(OFF, BSUM, DEG, N);
    k_scatter<<<cdiv(ET, 256), 256, 0, stream>>>(ei, E, ET, DEG, SSRC);

    // ---- layer 1: heads=2, C=64, ELU ----
    k_gemm<128, 32><<<cdiv(N, 32), 256, 0, stream>>>(x, W1, Hbuf, N);
    k_alpha<2><<<cdiv(N * 2, 4), 256, 0, stream>>>(Hbuf, as1, ad1, AS, AD, N);
    k_agg_fused<2, true><<<cdiv(N, 4), 256, 0, stream>>>(OFF, SSRC, Hbuf, AS, AD, b1, Zbuf, N);

    // ---- layer 2: heads=1, C=64, no activation ----
    k_gemm<64, 64><<<cdiv(N, 64), 256, 0, stream>>>(Zbuf, W2, Hbuf, N);
    k_alpha<1><<<cdiv(N, 4), 256, 0, stream>>>(Hbuf, as2, ad2, AS, AD, N);
    k_agg_fused<1, false><<<cdiv(N, 4), 256, 0, stream>>>(OFF, SSRC, Hbuf, AS, AD, b2, Zbuf, N);

    // ---- decode ----
    k_decode<<<cdiv(EL, 4), 256, 0, stream>>>(eli, Zbuf, (float*)d_out, EL);
}

// Round 4
// 515.542 us; speedup vs baseline: 2.4717x; 1.2670x over previous
//
#include <hip/hip_runtime.h>
#include <hip/hip_bf16.h>

#define NEG_SLOPE 0.2f
#define LRELU(v) ((v) > 0.f ? (v) : NEG_SLOPE * (v))
#define BBITS 7
#define BSZ 128  // nodes per bucket

static inline int cdiv(int a, int b) { return (a + b - 1) / b; }

// =================== wave-wide butterfly reductions (64 lanes) ===================
__device__ __forceinline__ float wmax(float v) {
#pragma unroll
    for (int o = 32; o; o >>= 1) v = fmaxf(v, __shfl_xor(v, o));
    return v;
}
__device__ __forceinline__ float wsum(float v) {
#pragma unroll
    for (int o = 32; o; o >>= 1) v += __shfl_xor(v, o);
    return v;
}

// =================== bucket-sort CSR build ===================
__global__ __launch_bounds__(256) void k_zero_int(int* p, int n) {
    int i = blockIdx.x * 256 + threadIdx.x;
    if (i < n) p[i] = 0;
}

// pass A: global bucket histogram via per-block LDS binning
__global__ __launch_bounds__(256) void k_bhist(const int* __restrict__ ei, int E, int ET, int NB,
                                               int* __restrict__ bcnt) {
    extern __shared__ int hist[];
    for (int i = threadIdx.x; i < NB; i += 256) hist[i] = 0;
    __syncthreads();
    int stride = gridDim.x * 256;
    for (int i = blockIdx.x * 256 + threadIdx.x; i < ET; i += stride) {
        int d = (i < E) ? ei[E + i] : (i - E);  // self loops appended
        atomicAdd(&hist[d >> BBITS], 1);
    }
    __syncthreads();
    for (int i = threadIdx.x; i < NB; i += 256) {
        int c = hist[i];
        if (c) atomicAdd(&bcnt[i], c);
    }
}

// tiny scan over NB buckets (LDS serial by thread 0 — NB ~ 800)
__global__ void k_scan_small(const int* __restrict__ bcnt, int NB,
                             int* __restrict__ boff, int* __restrict__ bcur,
                             int* __restrict__ offs, int N, int ET) {
    extern __shared__ int sm[];
    for (int i = threadIdx.x; i < NB; i += blockDim.x) sm[i] = bcnt[i];
    __syncthreads();
    if (threadIdx.x == 0) {
        int run = 0;
        for (int i = 0; i < NB; i++) { int c = sm[i]; sm[i] = run; run += c; }
    }
    __syncthreads();
    for (int i = threadIdx.x; i < NB; i += blockDim.x) { boff[i] = sm[i]; bcur[i] = sm[i]; }
    if (threadIdx.x == 0) { boff[NB] = ET; offs[N] = ET; }
}

// pass B1: scatter (d,s) pairs into bucket regions; per-block LDS count reserves
// a contiguous run per bucket -> writes are contiguous runs, L2 write-combined
__global__ __launch_bounds__(256) void k_bscatter(const int* __restrict__ ei, int E, int ET, int NB,
                                                  int* __restrict__ bcur,
                                                  long long* __restrict__ tmp) {
    extern __shared__ int sm2[];
    int* hist = sm2;
    int* cur = sm2 + NB;
    const int CH = 4096;
    int c0 = blockIdx.x * CH;
    int c1 = min(ET, c0 + CH);
    for (int i = threadIdx.x; i < NB; i += 256) hist[i] = 0;
    __syncthreads();
    for (int i = c0 + threadIdx.x; i < c1; i += 256) {
        int d = (i < E) ? ei[E + i] : (i - E);
        atomicAdd(&hist[d >> BBITS], 1);
    }
    __syncthreads();
    for (int i = threadIdx.x; i < NB; i += 256) {
        int c = hist[i];
        cur[i] = c ? atomicAdd(&bcur[i], c) : 0;
    }
    __syncthreads();
    for (int i = c0 + threadIdx.x; i < c1; i += 256) {
        int s = (i < E) ? ei[i] : (i - E);
        int d = (i < E) ? ei[E + i] : (i - E);
        int pos = atomicAdd(&cur[d >> BBITS], 1);
        tmp[pos] = ((long long)d << 32) | (unsigned)s;
    }
}

// pass B2: one block per bucket — per-node degree/cursors in LDS, scatter within
// the bucket's ~9KB output window (L2-local)
__global__ __launch_bounds__(256) void k_csrfin(const long long* __restrict__ tmp,
                                                const int* __restrict__ boff, int NB, int N,
                                                int* __restrict__ offs, int* __restrict__ ssrc) {
    __shared__ int deg[BSZ], cur[BSZ], sc[BSZ];
    int b = blockIdx.x;
    int node0 = b << BBITS;
    int nn = min(BSZ, N - node0);
    int r0 = boff[b], r1 = boff[b + 1];
    int t = threadIdx.x;
    if (t < BSZ) deg[t] = 0;
    __syncthreads();
    for (int i = r0 + t; i < r1; i += 256) {
        int d = (int)(tmp[i] >> 32);
        atomicAdd(&deg[d - node0], 1);
    }
    __syncthreads();
    if (t < BSZ) sc[t] = deg[t];
    __syncthreads();
    for (int o = 1; o < BSZ; o <<= 1) {  // Hillis-Steele inclusive scan
        int v = 0;
        if (t < BSZ && t >= o) v = sc[t - o];
        __syncthreads();
        if (t < BSZ) sc[t] += v;
        __syncthreads();
    }
    if (t < BSZ) {
        int ex = sc[t] - deg[t];  // exclusive
        cur[t] = r0 + ex;
        if (t < nn) offs[node0 + t] = r0 + ex;
    }
    __syncthreads();
    for (int i = r0 + t; i < r1; i += 256) {
        long long v = tmp[i];
        int d = (int)(v >> 32);
        int s = (int)(v & 0xffffffffLL);
        int pos = atomicAdd(&cur[d - node0], 1);
        ssrc[pos] = s;
    }
}

// =================== GEMM: h[N,M] = x[N,128] @ W[128,M] ===================
template <int M, int TR>
__global__ __launch_bounds__(256) void k_gemm(const float* __restrict__ x,
                                              const float* __restrict__ W,
                                              float* __restrict__ h, int N) {
    __shared__ float xs[128 * TR];  // xs[k][r], full K staged once
    __shared__ float ws[64 * M];    // ws[k][j], one 64-row half of W at a time
    int t = threadIdx.x;
    int row0 = blockIdx.x * TR;

    {   // load x tile transposed
        int r = t % TR;
        int kv0 = t / TR;
        const int GK = 256 / TR;
        int row = row0 + r;
        for (int kv = kv0; kv < 32; kv += GK) {
            float4 v = make_float4(0.f, 0.f, 0.f, 0.f);
            if (row < N) v = *(const float4*)(x + (size_t)row * 128 + kv * 4);
            xs[(kv * 4 + 0) * TR + r] = v.x;
            xs[(kv * 4 + 1) * TR + r] = v.y;
            xs[(kv * 4 + 2) * TR + r] = v.z;
            xs[(kv * 4 + 3) * TR + r] = v.w;
        }
    }

    constexpr int CQ = M / 4;
    int tx = t % CQ, ty = t / CQ;
    int j0 = tx * 4, r0 = ty * 4;
    float acc[4][4];
#pragma unroll
    for (int a = 0; a < 4; a++)
#pragma unroll
        for (int b = 0; b < 4; b++) acc[a][b] = 0.f;

    for (int ks = 0; ks < 128; ks += 64) {
        __syncthreads();
        const float4* wg = (const float4*)(W + (size_t)ks * M);
        float4* wl = (float4*)ws;
        for (int i = t; i < 64 * M / 4; i += 256) wl[i] = wg[i];
        __syncthreads();
#pragma unroll 8
        for (int k = 0; k < 64; k++) {
            float4 xv = *(const float4*)(xs + (ks + k) * TR + r0);
            float4 wv = *(const float4*)(ws + k * M + j0);
            float xr[4] = {xv.x, xv.y, xv.z, xv.w};
            float wr[4] = {wv.x, wv.y, wv.z, wv.w};
#pragma unroll
            for (int a = 0; a < 4; a++)
#pragma unroll
                for (int b = 0; b < 4; b++) acc[a][b] += xr[a] * wr[b];
        }
    }
#pragma unroll
    for (int a = 0; a < 4; a++) {
        int row = row0 + r0 + a;
        if (row < N)
            *(float4*)(h + (size_t)row * M + j0) =
                make_float4(acc[a][0], acc[a][1], acc[a][2], acc[a][3]);
    }
}

// =================== per-node attention projections ===================
template <int H>
__global__ __launch_bounds__(256) void k_alpha(const float* __restrict__ h,
                                               const float* __restrict__ a_src,
                                               const float* __restrict__ a_dst,
                                               float* __restrict__ as, float* __restrict__ ad,
                                               int N) {
    int wid = (blockIdx.x * 256 + threadIdx.x) >> 6;
    int lane = threadIdx.x & 63;
    if (wid >= N * H) return;
    int n = wid / H, hh = wid % H;
    float v = h[(size_t)n * (H * 64) + hh * 64 + lane];
    float s = v * a_src[hh * 64 + lane];
    float d = v * a_dst[hh * 64 + lane];
#pragma unroll
    for (int off = 32; off; off >>= 1) { s += __shfl_down(s, off); d += __shfl_down(d, off); }
    if (lane == 0) { as[wid] = s; ad[wid] = d; }
}

// =================== fused softmax + aggregation: one wave per dst node ===================
template <int H, bool ELU_ACT>
__global__ __launch_bounds__(256) void k_agg_fused(const int* __restrict__ offs,
                                                   const int* __restrict__ ssrc,
                                                   const float* __restrict__ h,
                                                   const float* __restrict__ as,
                                                   const float* __restrict__ ad,
                                                   const float* __restrict__ bias,
                                                   float* __restrict__ z, int N) {
    int d = (blockIdx.x * 256 + threadIdx.x) >> 6;
    int lane = threadIdx.x & 63;
    if (d >= N) return;
    float adh[H], m[H], den[H], acc[H];
#pragma unroll
    for (int hh = 0; hh < H; hh++) {
        adh[hh] = ad[d * H + hh];
        m[hh] = -1e30f; den[hh] = 0.f; acc[hh] = 0.f;
    }
    int e0 = offs[d], e1 = offs[d + 1];
    for (int cb = e0; cb < e1; cb += 64) {
        int ne = min(64, e1 - cb);
        int s_l = 0;
        float eh[H];
#pragma unroll
        for (int hh = 0; hh < H; hh++) eh[hh] = -1e30f;
        if (lane < ne) {
            s_l = ssrc[cb + lane];
#pragma unroll
            for (int hh = 0; hh < H; hh++) {
                float e = as[s_l * H + hh] + adh[hh];
                eh[hh] = LRELU(e);
            }
        }
        float p[H];
#pragma unroll
        for (int hh = 0; hh < H; hh++) {
            float cm = wmax(eh[hh]);
            float nm = fmaxf(m[hh], cm);
            float sc = __expf(m[hh] - nm);  // first chunk: exp(-1e30-nm) = 0
            acc[hh] *= sc; den[hh] *= sc;
            p[hh] = (lane < ne) ? __expf(eh[hh] - nm) : 0.f;
            den[hh] += wsum(p[hh]);
            m[hh] = nm;
        }
        int j = 0;
        for (; j + 4 <= ne; j += 4) {
            int ss[4]; float pp[4][H];
#pragma unroll
            for (int q = 0; q < 4; q++) {
                ss[q] = __shfl(s_l, j + q);
#pragma unroll
                for (int hh = 0; hh < H; hh++) pp[q][hh] = __shfl(p[hh], j + q);
            }
            float hv[4][H];
#pragma unroll
            for (int q = 0; q < 4; q++) {
                const float* hs = h + (size_t)ss[q] * (H * 64);
#pragma unroll
                for (int hh = 0; hh < H; hh++) hv[q][hh] = hs[hh * 64 + lane];
            }
#pragma unroll
            for (int q = 0; q < 4; q++)
#pragma unroll
                for (int hh = 0; hh < H; hh++) acc[hh] += pp[q][hh] * hv[q][hh];
        }
        for (; j < ne; j++) {
            int s = __shfl(s_l, j);
            const float* hs = h + (size_t)s * (H * 64);
#pragma unroll
            for (int hh = 0; hh < H; hh++) acc[hh] += __shfl(p[hh], j) * hs[hh * 64 + lane];
        }
    }
#pragma unroll
    for (int hh = 0; hh < H; hh++) {
        float v = acc[hh] / den[hh] + bias[hh * 64 + lane];
        if (ELU_ACT) v = v > 0.f ? v : expm1f(v);
        z[(size_t)d * (H * 64) + hh * 64 + lane] = v;
    }
}

// =================== decode: dot of endpoint embeddings ===================
__global__ __launch_bounds__(256) void k_decode(const int* __restrict__ eli,
                                                const float* __restrict__ z,
                                                float* __restrict__ out, int EL) {
    int wid = (blockIdx.x * 256 + threadIdx.x) >> 6;
    int lane = threadIdx.x & 63;
    if (wid >= EL) return;
    int a = eli[wid], b = eli[EL + wid];
    float p = z[(size_t)a * 64 + lane] * z[(size_t)b * 64 + lane];
#pragma unroll
    for (int off = 32; off; off >>= 1) p += __shfl_down(p, off);
    if (lane == 0) out[wid] = p;
}

extern "C" void kernel_launch(void* const* d_in, const int* in_sizes, int n_in,
                              void* d_out, int out_size, void* d_ws, size_t ws_size,
                              hipStream_t stream) {
    const float* x   = (const float*)d_in[0];
    const int*   ei  = (const int*)d_in[1];
    const int*   eli = (const int*)d_in[2];
    const float* W1  = (const float*)d_in[3];
    const float* as1 = (const float*)d_in[4];
    const float* ad1 = (const float*)d_in[5];
    const float* b1  = (const float*)d_in[6];
    const float* W2  = (const float*)d_in[7];
    const float* as2 = (const float*)d_in[8];
    const float* ad2 = (const float*)d_in[9];
    const float* b2  = (const float*)d_in[10];

    int N  = in_sizes[0] / 128;
    int E  = in_sizes[1] / 2;
    int EL = in_sizes[2] / 2;
    int ET = E + N;
    int NB = cdiv(N, BSZ);

    char* ws = (char*)d_ws;
    size_t off = 0;
    auto alloc = [&](size_t nbytes) -> void* {
        void* p = ws + off;
        off += (nbytes + 255) & ~(size_t)255;
        return p;
    };
    float*    Hbuf = (float*)alloc((size_t)N * 128 * 4);  // h1 then h2
    float*    Zbuf = (float*)alloc((size_t)N * 128 * 4);  // z1 then z2 (TMP aliases this)
    float*    AS   = (float*)alloc((size_t)N * 2 * 4);
    float*    AD   = (float*)alloc((size_t)N * 2 * 4);
    int*      OFF  = (int*)alloc((size_t)(N + 1) * 4);
    int*      SSRC = (int*)alloc((size_t)ET * 4);
    int*      BCNT = (int*)alloc((size_t)NB * 4);
    int*      BOFF = (int*)alloc((size_t)(NB + 1) * 4);
    int*      BCUR = (int*)alloc((size_t)NB * 4);
    long long* TMP = (long long*)Zbuf;  // (d,s) pairs; Zbuf unused until k_agg L1

    // ---- CSR build via bucket sort (shared by both layers) ----
    k_zero_int<<<cdiv(NB, 256), 256, 0, stream>>>(BCNT, NB);
    k_bhist<<<256, 256, NB * 4, stream>>>(ei, E, ET, NB, BCNT);
    k_scan_small<<<1, 256, NB * 4, stream>>>(BCNT, NB, BOFF, BCUR, OFF, N, ET);
    k_bscatter<<<cdiv(ET, 4096), 256, 2 * NB * 4, stream>>>(ei, E, ET, NB, BCUR, TMP);
    k_csrfin<<<NB, 256, 0, stream>>>(TMP, BOFF, NB, N, OFF, SSRC);

    // ---- layer 1: heads=2, C=64, ELU ----
    k_gemm<128, 32><<<cdiv(N, 32), 256, 0, stream>>>(x, W1, Hbuf, N);
    k_alpha<2><<<cdiv(N * 2, 4), 256, 0, stream>>>(Hbuf, as1, ad1, AS, AD, N);
    k_agg_fused<2, true><<<cdiv(N, 4), 256, 0, stream>>>(OFF, SSRC, Hbuf, AS, AD, b1, Zbuf, N);

    // ---- layer 2: heads=1, C=64, no activation ----
    k_gemm<64, 64><<<cdiv(N, 64), 256, 0, stream>>>(Zbuf, W2, Hbuf, N);
    k_alpha<1><<<cdiv(N, 4), 256, 0, stream>>>(Hbuf, as2, ad2, AS, AD, N);
    k_agg_fused<1, false><<<cdiv(N, 4), 256, 0, stream>>>(OFF, SSRC, Hbuf, AS, AD, b2, Zbuf, N);

    // ---- decode ----
    k_decode<<<cdiv(EL, 4), 256, 0, stream>>>(eli, Zbuf, (float*)d_out, EL);
}